// Round 17
// baseline (381.222 us; speedup 1.0000x reference)
//
#include <hip/hip_runtime.h>
#include <hip/hip_bf16.h>
#include <stdint.h>

#define T_TOK 8192
#define D_EMB 1024
#define H_DIM 2048
#define N1 4096
#define NE 8
#define RBLK 256     // router blocks; 32 tokens each
#define MAXTILES 72  // worst-case sum of ceil(cnt_e/256) = 64 + 8

typedef __bf16 bf16_t;
typedef __bf16 bf16x8 __attribute__((ext_vector_type(8)));
typedef __bf16 bf16x4 __attribute__((ext_vector_type(4)));
typedef float f32x4 __attribute__((ext_vector_type(4)));

typedef __attribute__((address_space(1))) void gvoid_t;
typedef __attribute__((address_space(3))) void svoid_t;

__device__ __forceinline__ void gld_lds16(bf16_t* lds, const bf16_t* g) {
  __builtin_amdgcn_global_load_lds((gvoid_t*)g, (svoid_t*)lds, 16, 0, 0);
}

// ---------------- fused pre-pass: router (fused x->bf16) + both weight converts ----------
template <bool ILV, int LOGNX, int LOGNY>
__device__ __forceinline__ void cvt_body(char* smem, const float* __restrict__ src,
                                         bf16_t* __restrict__ dst, int K, int N, int b) {
  bf16_t (*tile)[72] = (bf16_t(*)[72])smem;  // 64 x 72 bf16 = 9216 B
  int bx = b & ((1 << LOGNX) - 1);
  int rest = b >> LOGNX;
  int by = rest & ((1 << LOGNY) - 1);
  int e = rest >> LOGNY;
  int k0 = by << 6, j0 = bx << 6;
  const float* s = src + (size_t)e * K * N;
  bf16_t* d = dst + (size_t)e * K * N;
  int t = threadIdx.x;
  int c4 = t & 15, r0 = t >> 4;
#pragma unroll
  for (int i = 0; i < 4; i++) {
    int r = r0 + i * 16;
    float4 v = *(const float4*)&s[(size_t)(k0 + r) * N + j0 + c4 * 4];
    bf16x4 o;
    o[0] = (bf16_t)v.x; o[1] = (bf16_t)v.y; o[2] = (bf16_t)v.z; o[3] = (bf16_t)v.w;
    *(bf16x4*)&tile[r][c4 * 4] = o;
  }
  __syncthreads();
  int n = t >> 2, kc = t & 3;
  int j = j0 + n, np_;
  if (ILV) {
    int half = N >> 1;
    if (j < half) np_ = ((j >> 4) << 5) | (j & 15);
    else { int jm = j - half; np_ = ((jm >> 4) << 5) | 16 | (jm & 15); }
  } else np_ = j;
  bf16x8 w0, w1;
#pragma unroll
  for (int q = 0; q < 8; q++) w0[q] = tile[kc * 16 + q][n];
#pragma unroll
  for (int q = 0; q < 8; q++) w1[q] = tile[kc * 16 + 8 + q][n];
  *(bf16x8*)&d[(size_t)np_ * K + k0 + kc * 16] = w0;
  *(bf16x8*)&d[(size_t)np_ * K + k0 + kc * 16 + 8] = w1;
}

__device__ __forceinline__ void router_body(char* smem, const float* __restrict__ x,
                                            const float* __restrict__ wg,
                                            bf16_t* __restrict__ xb,
                                            int* __restrict__ tki,
                                            float* __restrict__ tkp,
                                            int* __restrict__ blockhist, int b) {
  float* wgl = (float*)smem;                 // 32 KB [e][d]
  int* hist = (int*)(smem + NE * D_EMB * 4); // 32 B
  int t = threadIdx.x;
  if (t < NE) hist[t] = 0;
  for (int i = t; i < NE * D_EMB; i += 256) {
    int e = i >> 10, d = i & 1023;
    wgl[i] = wg[d * NE + e];
  }
  __syncthreads();
  int wave = t >> 6, lane = t & 63;
#pragma unroll
  for (int it = 0; it < 8; it++) {
    int tok = b * 32 + wave * 8 + it;
    const float* xr = x + (size_t)tok * D_EMB;
    bf16_t* xbr = xb + (size_t)tok * D_EMB;
    float acc[NE] = {};
    for (int d = lane; d < D_EMB; d += 64) {
      float xv = xr[d];
#pragma unroll
      for (int e = 0; e < NE; e++) acc[e] += xv * wgl[e * D_EMB + d];
    }
#pragma unroll
    for (int j = 0; j < 4; j++) {
      int d4 = j * 64 + lane;
      float4 v = ((const float4*)xr)[d4];
      bf16x4 o;
      o[0] = (bf16_t)v.x; o[1] = (bf16_t)v.y; o[2] = (bf16_t)v.z; o[3] = (bf16_t)v.w;
      *(bf16x4*)(xbr + d4 * 4) = o;
    }
#pragma unroll
    for (int e = 0; e < NE; e++) {
#pragma unroll
      for (int off = 32; off; off >>= 1) acc[e] += __shfl_xor(acc[e], off);
    }
    if (lane == 0) {
      int i0 = 0; float s0 = acc[0];
#pragma unroll
      for (int e = 1; e < NE; e++) if (acc[e] > s0) { s0 = acc[e]; i0 = e; }
      int i1 = -1; float s1 = -3.4e38f;
#pragma unroll
      for (int e = 0; e < NE; e++) if (e != i0 && acc[e] > s1) { s1 = acc[e]; i1 = e; }
      float ex = __expf(s1 - s0);
      float inv = 1.f / (1.f + ex);
      tki[tok * 2] = i0; tki[tok * 2 + 1] = i1;
      tkp[tok * 2] = inv; tkp[tok * 2 + 1] = ex * inv;
      atomicAdd(&hist[i0], 1); atomicAdd(&hist[i1], 1);  // LDS only
    }
  }
  __syncthreads();
  if (t < NE) blockhist[b * NE + t] = hist[t];
}

__global__ __launch_bounds__(256) void k_pre(const float* __restrict__ x,
                                             const float* __restrict__ wg,
                                             const float* __restrict__ w12,
                                             const float* __restrict__ w3,
                                             bf16_t* __restrict__ xb,
                                             bf16_t* __restrict__ w12b,
                                             bf16_t* __restrict__ w3b,
                                             int* __restrict__ tki,
                                             float* __restrict__ tkp,
                                             int* __restrict__ blockhist) {
  __shared__ __align__(16) char smem[NE * D_EMB * 4 + 64];  // union: wgl+hist | cvt tile
  int bid = blockIdx.x;
  if (bid < RBLK) {
    router_body(smem, x, wg, xb, tki, tkp, blockhist, bid);
  } else if (bid < RBLK + 8192) {
    cvt_body<true, 6, 4>(smem, w12, w12b, D_EMB, N1, bid - RBLK);      // 64x16x8 tiles
  } else {
    cvt_body<false, 4, 5>(smem, w3, w3b, H_DIM, D_EMB, bid - RBLK - 8192);  // 16x32x8
  }
}

// ------- scatter (fused offsets): per-block prefix from blockhist; block 0 publishes ----
__global__ __launch_bounds__(64) void k_scatter(const int* __restrict__ bh,
                                                const int* __restrict__ tki,
                                                int* __restrict__ tlist,
                                                int* __restrict__ tok2pos,
                                                int* __restrict__ offsets,
                                                int* __restrict__ tilestart) {
  __shared__ int tot[NE], pre[NE], soff[NE + 1], bb[NE], lh[NE];
  int t = threadIdx.x;
  int b = blockIdx.x;
  if (t < NE) {
    lh[t] = 0;
    int p = 0, s = 0;
    for (int i = 0; i < RBLK; i++) {
      int v = bh[i * NE + t];
      s += v;
      p += (i < b) ? v : 0;
    }
    tot[t] = s;
    pre[t] = p;
  }
  __syncthreads();
  if (t == 0) {
    int s = 0;
#pragma unroll
    for (int i = 0; i < NE; i++) { soff[i] = s; s += tot[i]; }
    soff[NE] = s;
    if (b == 0) {
#pragma unroll
      for (int i = 0; i <= NE; i++) offsets[i] = soff[i];
      int ts = 0;
#pragma unroll
      for (int i = 0; i < NE; i++) { tilestart[i] = ts; ts += (tot[i] + 255) >> 8; }
      tilestart[NE] = ts;
    }
  }
  __syncthreads();
  if (t < NE) bb[t] = soff[t] + pre[t];
  __syncthreads();
  if (t < 32) {
    int tok = b * 32 + t;
#pragma unroll
    for (int k = 0; k < 2; k++) {
      int e = tki[tok * 2 + k];
      int r = atomicAdd(&lh[e], 1);
      int pos = bb[e] + r;
      tlist[pos] = tok;
      tok2pos[tok * 2 + k] = pos;
    }
  }
}

// ======== grouped GEMM, 256x256 tile, BK=64, 16 waves (4Mx4N, 64x64/wave) ========
// R15 body (best measured: 178us, MfmaUtil 35.5, Occ 38, conflicts 0). XCD swizzle
// REVERTED (R16: FETCH 190->202MB, dur slightly worse — default placement wins).
// Change vs R15: dropped the sched_barrier between ks0-MFMA and ks1-reads so the
// compiler can hoist ks1 ds_reads under ks0 MFMAs (read-read, no hazard; fine
// lgkmcnt scheduling per m97). Rule-#18 fences after inline lgkmcnt kept.
template <int PHASE>
__global__ __launch_bounds__(1024, 4) void k_gemm8(const bf16_t* __restrict__ A,
                                                   const bf16_t* __restrict__ B,
                                                   const int* __restrict__ offsets,
                                                   const int* __restrict__ tilestart,
                                                   const int* __restrict__ tlist,
                                                   bf16_t* __restrict__ hb,
                                                   bf16_t* __restrict__ partial) {
  constexpr int AK = (PHASE == 1) ? D_EMB : H_DIM;
  constexpr int NT = AK / 64;                        // K-tiles
  constexpr int BNT = (PHASE == 1) ? N1 : D_EMB;
  constexpr int NX = (PHASE == 1) ? 16 : 4;          // n-tiles (256 cols each)
  const int bid = blockIdx.x;
  const int tile = bid / NX;
  const int nx = bid - tile * NX;
  if (tile >= tilestart[NE]) return;
  int e = 0;
#pragma unroll
  for (int i = 1; i < NE; i++) e += (tile >= tilestart[i]) ? 1 : 0;
  const int seg = offsets[e];
  const int cnt = offsets[e + 1] - seg;
  const int mt = tile - tilestart[e];
  if (mt * 256 >= cnt) return;  // safety
  const int n0 = nx << 8;
  const bf16_t* Bexp = B + (size_t)e * (size_t)AK * BNT;

  __shared__ bf16_t As[2][256 * 64];   // 32 KB each buf, row stride 64 bf16 = 128 B
  __shared__ bf16_t Bs[2][256 * 64];

  const int tid = threadIdx.x;
  const int wave = tid >> 6, lane = tid & 63;
  const int wr = wave >> 2, wc = wave & 3;   // 4M x 4N

  // ---- staging: 1024 thr x 2 chunks x 16B per matrix; LDS dest linear (wave-uniform
  // base; HW appends lane*16B); global source carries the inverse swizzle.
  const bf16_t* srcA[2];
  const bf16_t* srcB[2];
#pragma unroll
  for (int i = 0; i < 2; i++) {
    int chunk = i * 1024 + tid;         // 0..2047
    int row = chunk >> 3;               // 0..255
    int cphys = (chunk & 7) * 16;       // byte col in 128B row
    int clog = cphys ^ ((row & 7) << 4);
    int rb = mt * 256 + row;
    int rbc = (rb < cnt) ? rb : (cnt - 1);
    if (PHASE == 1) {
      int tok = tlist[seg + rbc];
      srcA[i] = A + (size_t)tok * AK + (clog >> 1);
    } else {
      srcA[i] = A + (size_t)(seg + rbc) * AK + (clog >> 1);
    }
    srcB[i] = Bexp + (size_t)(n0 + row) * AK + (clog >> 1);
  }

#define STAGE4(cur, kt)                                                        \
  {                                                                            \
    const int koff_ = (kt) * 64;                                               \
    _Pragma("unroll") for (int i_ = 0; i_ < 2; i_++)                           \
        gld_lds16(&As[cur][(i_ * 1024 + wave * 64) * 8], srcA[i_] + koff_);    \
    _Pragma("unroll") for (int i_ = 0; i_ < 2; i_++)                           \
        gld_lds16(&Bs[cur][(i_ * 1024 + wave * 64) * 8], srcB[i_] + koff_);    \
  }

  // ---- fragment read offsets (swizzled)
  const int fr = lane & 15;
  const int fkb = (lane >> 4) * 16;     // byte k-chunk within 32-k step
  int aoff[2][4], boff[2][4];
#pragma unroll
  for (int ks = 0; ks < 2; ks++) {
#pragma unroll
    for (int mf = 0; mf < 4; mf++) {
      int row = wr * 64 + mf * 16 + fr;
      int cl = ks * 64 + fkb;
      aoff[ks][mf] = row * 128 + (cl ^ ((row & 7) << 4));
    }
#pragma unroll
    for (int nf = 0; nf < 4; nf++) {
      int row = wc * 64 + nf * 16 + fr;
      int cl = ks * 64 + fkb;
      boff[ks][nf] = row * 128 + (cl ^ ((row & 7) << 4));
    }
  }

  f32x4 acc[4][4] = {};

#define DO_MFMA16(af, bv)                                                      \
  __builtin_amdgcn_s_setprio(1);                                               \
  _Pragma("unroll") for (int i_ = 0; i_ < 4; i_++)                             \
  _Pragma("unroll") for (int nf_ = 0; nf_ < 4; nf_++)                          \
      acc[i_][nf_] = __builtin_amdgcn_mfma_f32_16x16x32_bf16(                  \
          af[i_], bv[nf_], acc[i_][nf_], 0, 0, 0);                             \
  __builtin_amdgcn_s_setprio(0);

  // prologue: stage tiles 0 and 1; wait tile 0 only (counted vmcnt: 8 out -> 4)
  STAGE4(0, 0);
  STAGE4(1, 1);
  asm volatile("s_waitcnt vmcnt(4)" ::: "memory");
  __builtin_amdgcn_s_barrier();

  for (int t = 0; t < NT; ++t) {
    const int cur = t & 1;
    const char* asb = (const char*)&As[cur][0];
    const char* bsb = (const char*)&Bs[cur][0];
    bf16x8 a0[4], b0[4], a1[4], b1[4];

    // ks0 + ks1 reads and ks0 MFMA in one scheduling region: compiler may hoist
    // ks1 reads under ks0 MFMA (fine-grained lgkmcnt; no hazard).
#pragma unroll
    for (int nf = 0; nf < 4; nf++) b0[nf] = *(const bf16x8*)(bsb + boff[0][nf]);
#pragma unroll
    for (int i = 0; i < 4; i++) a0[i] = *(const bf16x8*)(asb + aoff[0][i]);
    DO_MFMA16(a0, b0);
#pragma unroll
    for (int nf = 0; nf < 4; nf++) b1[nf] = *(const bf16x8*)(bsb + boff[1][nf]);
#pragma unroll
    for (int i = 0; i < 4; i++) a1[i] = *(const bf16x8*)(asb + aoff[1][i]);
    __builtin_amdgcn_sched_barrier(0);
    asm volatile("s_waitcnt lgkmcnt(0)" ::: "memory");
    __builtin_amdgcn_s_barrier();          // all waves done reading buf[cur]
    if (t + 2 < NT) STAGE4(cur, t + 2);
    __builtin_amdgcn_sched_barrier(0);
    DO_MFMA16(a1, b1);
    if (t + 2 < NT) {
      asm volatile("s_waitcnt vmcnt(4)" ::: "memory");   // tile t+1 landed
      __builtin_amdgcn_s_barrier();
    } else if (t + 1 < NT) {
      asm volatile("s_waitcnt vmcnt(0)" ::: "memory");   // last tile landed
      __builtin_amdgcn_s_barrier();
    }
    __builtin_amdgcn_sched_barrier(0);
  }

  // ---- epilogue ----
  if (PHASE == 1) {
#pragma unroll
    for (int mf = 0; mf < 4; mf++) {
      int rbase = mt * 256 + wr * 64 + mf * 16 + ((lane >> 4) << 2);
#pragma unroll
      for (int p = 0; p < 2; p++) {
        int hcol = (n0 >> 1) + wc * 32 + p * 16 + fr;
#pragma unroll
        for (int j = 0; j < 4; j++) {
          int r = rbase + j;
          if (r < cnt) {
            float g = acc[mf][2 * p][j];
            float v = acc[mf][2 * p + 1][j];
            float s = g / (1.f + __expf(-g));
            hb[(size_t)(seg + r) * H_DIM + hcol] = (bf16_t)(s * v);
          }
        }
      }
    }
  } else {
#pragma unroll
    for (int mf = 0; mf < 4; mf++) {
      int rbase = mt * 256 + wr * 64 + mf * 16 + ((lane >> 4) << 2);
#pragma unroll
      for (int j = 0; j < 4; j++) {
        int r = rbase + j;
        if (r < cnt) {
          bf16_t* op = partial + (size_t)(seg + r) * D_EMB + n0 + wc * 64 + fr;
#pragma unroll
          for (int nf = 0; nf < 4; nf++) op[nf * 16] = (bf16_t)acc[mf][nf][j];
        }
      }
    }
  }
#undef STAGE4
#undef DO_MFMA16
}

// ---------------- combine: out[tok] = p0*partial[pos0] + p1*partial[pos1] (bf16 in) ----
__global__ __launch_bounds__(256) void k_combine(const bf16_t* __restrict__ partial,
                                                 const float* __restrict__ tkp,
                                                 const int* __restrict__ tok2pos,
                                                 float* __restrict__ out) {
  int i = blockIdx.x * 256 + threadIdx.x;  // T_TOK*128 threads, 8 elems each
  int tok = i >> 7;
  int c8 = i & 127;
  int p0 = tok2pos[tok * 2], p1 = tok2pos[tok * 2 + 1];
  float w0 = tkp[tok * 2], w1 = tkp[tok * 2 + 1];
  bf16x8 a = *(const bf16x8*)(partial + (size_t)p0 * D_EMB + c8 * 8);
  bf16x8 b = *(const bf16x8*)(partial + (size_t)p1 * D_EMB + c8 * 8);
  float4 o0, o1;
  o0.x = w0 * (float)a[0] + w1 * (float)b[0];
  o0.y = w0 * (float)a[1] + w1 * (float)b[1];
  o0.z = w0 * (float)a[2] + w1 * (float)b[2];
  o0.w = w0 * (float)a[3] + w1 * (float)b[3];
  o1.x = w0 * (float)a[4] + w1 * (float)b[4];
  o1.y = w0 * (float)a[5] + w1 * (float)b[5];
  o1.z = w0 * (float)a[6] + w1 * (float)b[6];
  o1.w = w0 * (float)a[7] + w1 * (float)b[7];
  float4* op = (float4*)(out + (size_t)tok * D_EMB + c8 * 8);
  op[0] = o0;
  op[1] = o1;
}

extern "C" void kernel_launch(void* const* d_in, const int* in_sizes, int n_in,
                              void* d_out, int out_size, void* d_ws, size_t ws_size,
                              hipStream_t stream) {
  (void)in_sizes; (void)n_in; (void)ws_size; (void)out_size;
  const float* x   = (const float*)d_in[0];
  const float* w12 = (const float*)d_in[1];
  const float* w3  = (const float*)d_in[2];
  const float* wg  = (const float*)d_in[3];
  float* out = (float*)d_out;
  char* ws = (char*)d_ws;

  const size_t OFF_XB   = 0;                       // xb: 16 MiB
  const size_t OFF_W12B = 16777216;                // w12b: 64 MiB
  const size_t OFF_W3B  = OFF_W12B + 67108864;     // w3b: 32 MiB
  const size_t OFF_HB   = OFF_W3B + 33554432;      // hb: 64 MiB
  const size_t OFF_META = OFF_HB + 67108864;
  // partial (bf16 16384x1024 = 32 MiB) overlaps [xb|w12b-lo] — dead by gemm2 time.
  const size_t OFF_PART = 0;

  bf16_t* xb   = (bf16_t*)(ws + OFF_XB);
  bf16_t* w12b = (bf16_t*)(ws + OFF_W12B);
  bf16_t* w3b  = (bf16_t*)(ws + OFF_W3B);
  bf16_t* hb   = (bf16_t*)(ws + OFF_HB);
  bf16_t* partial = (bf16_t*)(ws + OFF_PART);
  int*   offsets   = (int*)(ws + OFF_META);                 // 64 B
  int*   blockhist = (int*)(ws + OFF_META + 64);            // 8 KiB
  int*   tilestart = (int*)(ws + OFF_META + 16448);         // 64 B
  int*   tki       = (int*)(ws + OFF_META + 32768);
  float* tkp       = (float*)(ws + OFF_META + 32768 + 65536);
  int*   tlist     = (int*)(ws + OFF_META + 32768 + 2 * 65536);
  int*   tok2pos   = (int*)(ws + OFF_META + 32768 + 3 * 65536);

  k_pre<<<RBLK + 8192 + 4096, 256, 0, stream>>>(x, wg, w12, w3, xb, w12b, w3b,
                                                tki, tkp, blockhist);
  k_scatter<<<RBLK, 64, 0, stream>>>(blockhist, tki, tlist, tok2pos, offsets, tilestart);
  k_gemm8<1><<<MAXTILES * 16, 1024, 0, stream>>>(xb, w12b, offsets, tilestart, tlist, hb, nullptr);
  k_gemm8<2><<<MAXTILES * 4, 1024, 0, stream>>>(hb, w3b, offsets, tilestart, tlist, nullptr, partial);
  k_combine<<<T_TOK / 2, 256, 0, stream>>>(partial, tkp, tok2pos, out);
}

// Round 18
// 365.170 us; speedup vs baseline: 1.0440x; 1.0440x over previous
//
#include <hip/hip_runtime.h>
#include <hip/hip_bf16.h>
#include <stdint.h>

#define T_TOK 8192
#define D_EMB 1024
#define H_DIM 2048
#define N1 4096
#define NE 8
#define RBLK 256     // router blocks; 32 tokens each
#define MAXTILES 72  // worst-case sum of ceil(cnt_e/256) = 64 + 8
#define HALFP (16384 * 1024)  // elements per split-K partial half

typedef __bf16 bf16_t;
typedef __bf16 bf16x8 __attribute__((ext_vector_type(8)));
typedef __bf16 bf16x4 __attribute__((ext_vector_type(4)));
typedef float f32x4 __attribute__((ext_vector_type(4)));

typedef __attribute__((address_space(1))) void gvoid_t;
typedef __attribute__((address_space(3))) void svoid_t;

__device__ __forceinline__ void gld_lds16(bf16_t* lds, const bf16_t* g) {
  __builtin_amdgcn_global_load_lds((gvoid_t*)g, (svoid_t*)lds, 16, 0, 0);
}

// ---------------- fused pre-pass: router (fused x->bf16) + both weight converts ----------
template <bool ILV, int LOGNX, int LOGNY>
__device__ __forceinline__ void cvt_body(char* smem, const float* __restrict__ src,
                                         bf16_t* __restrict__ dst, int K, int N, int b) {
  bf16_t (*tile)[72] = (bf16_t(*)[72])smem;  // 64 x 72 bf16 = 9216 B
  int bx = b & ((1 << LOGNX) - 1);
  int rest = b >> LOGNX;
  int by = rest & ((1 << LOGNY) - 1);
  int e = rest >> LOGNY;
  int k0 = by << 6, j0 = bx << 6;
  const float* s = src + (size_t)e * K * N;
  bf16_t* d = dst + (size_t)e * K * N;
  int t = threadIdx.x;
  int c4 = t & 15, r0 = t >> 4;
#pragma unroll
  for (int i = 0; i < 4; i++) {
    int r = r0 + i * 16;
    float4 v = *(const float4*)&s[(size_t)(k0 + r) * N + j0 + c4 * 4];
    bf16x4 o;
    o[0] = (bf16_t)v.x; o[1] = (bf16_t)v.y; o[2] = (bf16_t)v.z; o[3] = (bf16_t)v.w;
    *(bf16x4*)&tile[r][c4 * 4] = o;
  }
  __syncthreads();
  int n = t >> 2, kc = t & 3;
  int j = j0 + n, np_;
  if (ILV) {
    int half = N >> 1;
    if (j < half) np_ = ((j >> 4) << 5) | (j & 15);
    else { int jm = j - half; np_ = ((jm >> 4) << 5) | 16 | (jm & 15); }
  } else np_ = j;
  bf16x8 w0, w1;
#pragma unroll
  for (int q = 0; q < 8; q++) w0[q] = tile[kc * 16 + q][n];
#pragma unroll
  for (int q = 0; q < 8; q++) w1[q] = tile[kc * 16 + 8 + q][n];
  *(bf16x8*)&d[(size_t)np_ * K + k0 + kc * 16] = w0;
  *(bf16x8*)&d[(size_t)np_ * K + k0 + kc * 16 + 8] = w1;
}

__device__ __forceinline__ void router_body(char* smem, const float* __restrict__ x,
                                            const float* __restrict__ wg,
                                            bf16_t* __restrict__ xb,
                                            int* __restrict__ tki,
                                            float* __restrict__ tkp,
                                            int* __restrict__ blockhist, int b) {
  float* wgl = (float*)smem;                 // 32 KB [e][d]
  int* hist = (int*)(smem + NE * D_EMB * 4); // 32 B
  int t = threadIdx.x;
  if (t < NE) hist[t] = 0;
  for (int i = t; i < NE * D_EMB; i += 256) {
    int e = i >> 10, d = i & 1023;
    wgl[i] = wg[d * NE + e];
  }
  __syncthreads();
  int wave = t >> 6, lane = t & 63;
#pragma unroll
  for (int it = 0; it < 8; it++) {
    int tok = b * 32 + wave * 8 + it;
    const float* xr = x + (size_t)tok * D_EMB;
    bf16_t* xbr = xb + (size_t)tok * D_EMB;
    float acc[NE] = {};
    for (int d = lane; d < D_EMB; d += 64) {
      float xv = xr[d];
#pragma unroll
      for (int e = 0; e < NE; e++) acc[e] += xv * wgl[e * D_EMB + d];
    }
#pragma unroll
    for (int j = 0; j < 4; j++) {
      int d4 = j * 64 + lane;
      float4 v = ((const float4*)xr)[d4];
      bf16x4 o;
      o[0] = (bf16_t)v.x; o[1] = (bf16_t)v.y; o[2] = (bf16_t)v.z; o[3] = (bf16_t)v.w;
      *(bf16x4*)(xbr + d4 * 4) = o;
    }
#pragma unroll
    for (int e = 0; e < NE; e++) {
#pragma unroll
      for (int off = 32; off; off >>= 1) acc[e] += __shfl_xor(acc[e], off);
    }
    if (lane == 0) {
      int i0 = 0; float s0 = acc[0];
#pragma unroll
      for (int e = 1; e < NE; e++) if (acc[e] > s0) { s0 = acc[e]; i0 = e; }
      int i1 = -1; float s1 = -3.4e38f;
#pragma unroll
      for (int e = 0; e < NE; e++) if (e != i0 && acc[e] > s1) { s1 = acc[e]; i1 = e; }
      float ex = __expf(s1 - s0);
      float inv = 1.f / (1.f + ex);
      tki[tok * 2] = i0; tki[tok * 2 + 1] = i1;
      tkp[tok * 2] = inv; tkp[tok * 2 + 1] = ex * inv;
      atomicAdd(&hist[i0], 1); atomicAdd(&hist[i1], 1);  // LDS only
    }
  }
  __syncthreads();
  if (t < NE) blockhist[b * NE + t] = hist[t];
}

__global__ __launch_bounds__(256) void k_pre(const float* __restrict__ x,
                                             const float* __restrict__ wg,
                                             const float* __restrict__ w12,
                                             const float* __restrict__ w3,
                                             bf16_t* __restrict__ xb,
                                             bf16_t* __restrict__ w12b,
                                             bf16_t* __restrict__ w3b,
                                             int* __restrict__ tki,
                                             float* __restrict__ tkp,
                                             int* __restrict__ blockhist) {
  __shared__ __align__(16) char smem[NE * D_EMB * 4 + 64];  // union: wgl+hist | cvt tile
  int bid = blockIdx.x;
  if (bid < RBLK) {
    router_body(smem, x, wg, xb, tki, tkp, blockhist, bid);
  } else if (bid < RBLK + 8192) {
    cvt_body<true, 6, 4>(smem, w12, w12b, D_EMB, N1, bid - RBLK);      // 64x16x8 tiles
  } else {
    cvt_body<false, 4, 5>(smem, w3, w3b, H_DIM, D_EMB, bid - RBLK - 8192);  // 16x32x8
  }
}

// ------- scatter (fused offsets): per-block prefix from blockhist; block 0 publishes ----
__global__ __launch_bounds__(64) void k_scatter(const int* __restrict__ bh,
                                                const int* __restrict__ tki,
                                                int* __restrict__ tlist,
                                                int* __restrict__ tok2pos,
                                                int* __restrict__ offsets,
                                                int* __restrict__ tilestart) {
  __shared__ int tot[NE], pre[NE], soff[NE + 1], bb[NE], lh[NE];
  int t = threadIdx.x;
  int b = blockIdx.x;
  if (t < NE) {
    lh[t] = 0;
    int p = 0, s = 0;
    for (int i = 0; i < RBLK; i++) {
      int v = bh[i * NE + t];
      s += v;
      p += (i < b) ? v : 0;
    }
    tot[t] = s;
    pre[t] = p;
  }
  __syncthreads();
  if (t == 0) {
    int s = 0;
#pragma unroll
    for (int i = 0; i < NE; i++) { soff[i] = s; s += tot[i]; }
    soff[NE] = s;
    if (b == 0) {
#pragma unroll
      for (int i = 0; i <= NE; i++) offsets[i] = soff[i];
      int ts = 0;
#pragma unroll
      for (int i = 0; i < NE; i++) { tilestart[i] = ts; ts += (tot[i] + 255) >> 8; }
      tilestart[NE] = ts;
    }
  }
  __syncthreads();
  if (t < NE) bb[t] = soff[t] + pre[t];
  __syncthreads();
  if (t < 32) {
    int tok = b * 32 + t;
#pragma unroll
    for (int k = 0; k < 2; k++) {
      int e = tki[tok * 2 + k];
      int r = atomicAdd(&lh[e], 1);
      int pos = bb[e] + r;
      tlist[pos] = tok;
      tok2pos[tok * 2 + k] = pos;
    }
  }
}

// ======== grouped GEMM, 256x256 tile, BK=64, 16 waves (4Mx4N, 64x64/wave) ========
// R15/R17 verified body. PHASE 2 adds SPLIT-K=2: each block computes a 1024-wide K
// half (same NT=16 loop as PHASE 1) into its own partial half-buffer — fixes the
// 272-blocks-on-256-CUs 2-round imbalance (~120us -> ~90us predicted).
template <int PHASE>
__global__ __launch_bounds__(1024, 4) void k_gemm8(const bf16_t* __restrict__ A,
                                                   const bf16_t* __restrict__ B,
                                                   const int* __restrict__ offsets,
                                                   const int* __restrict__ tilestart,
                                                   const int* __restrict__ tlist,
                                                   bf16_t* __restrict__ hb,
                                                   bf16_t* __restrict__ partial) {
  constexpr int AK = (PHASE == 1) ? D_EMB : H_DIM;        // full K of A rows
  constexpr int KLEN = (PHASE == 1) ? AK : AK / 2;        // K handled per block (1024)
  constexpr int NT = KLEN / 64;                           // 16 K-tiles both phases
  constexpr int BNT = (PHASE == 1) ? N1 : D_EMB;
  constexpr int NX = (PHASE == 1) ? 16 : 4;               // n-tiles (256 cols each)
  int bid = blockIdx.x;
  int khalf = 0;
  if (PHASE == 2) {
    khalf = (bid >= NX * MAXTILES) ? 1 : 0;
    bid -= khalf * NX * MAXTILES;
  }
  const int tile = bid / NX;
  const int nx = bid - tile * NX;
  if (tile >= tilestart[NE]) return;
  int e = 0;
#pragma unroll
  for (int i = 1; i < NE; i++) e += (tile >= tilestart[i]) ? 1 : 0;
  const int seg = offsets[e];
  const int cnt = offsets[e + 1] - seg;
  const int mt = tile - tilestart[e];
  if (mt * 256 >= cnt) return;  // safety
  const int n0 = nx << 8;
  const size_t kbase = (size_t)khalf * KLEN;              // element offset in K
  const bf16_t* Bexp = B + (size_t)e * (size_t)AK * BNT;

  __shared__ bf16_t As[2][256 * 64];   // 32 KB each buf, row stride 64 bf16 = 128 B
  __shared__ bf16_t Bs[2][256 * 64];

  const int tid = threadIdx.x;
  const int wave = tid >> 6, lane = tid & 63;
  const int wr = wave >> 2, wc = wave & 3;   // 4M x 4N

  // ---- staging: 1024 thr x 2 chunks x 16B per matrix; LDS dest linear (wave-uniform
  // base; HW appends lane*16B); global source carries the inverse swizzle.
  const bf16_t* srcA[2];
  const bf16_t* srcB[2];
#pragma unroll
  for (int i = 0; i < 2; i++) {
    int chunk = i * 1024 + tid;         // 0..2047
    int row = chunk >> 3;               // 0..255
    int cphys = (chunk & 7) * 16;       // byte col in 128B row
    int clog = cphys ^ ((row & 7) << 4);
    int rb = mt * 256 + row;
    int rbc = (rb < cnt) ? rb : (cnt - 1);
    if (PHASE == 1) {
      int tok = tlist[seg + rbc];
      srcA[i] = A + (size_t)tok * AK + kbase + (clog >> 1);
    } else {
      srcA[i] = A + (size_t)(seg + rbc) * AK + kbase + (clog >> 1);
    }
    srcB[i] = Bexp + (size_t)(n0 + row) * AK + kbase + (clog >> 1);
  }

#define STAGE4(cur, kt)                                                        \
  {                                                                            \
    const int koff_ = (kt) * 64;                                               \
    _Pragma("unroll") for (int i_ = 0; i_ < 2; i_++)                           \
        gld_lds16(&As[cur][(i_ * 1024 + wave * 64) * 8], srcA[i_] + koff_);    \
    _Pragma("unroll") for (int i_ = 0; i_ < 2; i_++)                           \
        gld_lds16(&Bs[cur][(i_ * 1024 + wave * 64) * 8], srcB[i_] + koff_);    \
  }

  // ---- fragment read offsets (swizzled)
  const int fr = lane & 15;
  const int fkb = (lane >> 4) * 16;     // byte k-chunk within 32-k step
  int aoff[2][4], boff[2][4];
#pragma unroll
  for (int ks = 0; ks < 2; ks++) {
#pragma unroll
    for (int mf = 0; mf < 4; mf++) {
      int row = wr * 64 + mf * 16 + fr;
      int cl = ks * 64 + fkb;
      aoff[ks][mf] = row * 128 + (cl ^ ((row & 7) << 4));
    }
#pragma unroll
    for (int nf = 0; nf < 4; nf++) {
      int row = wc * 64 + nf * 16 + fr;
      int cl = ks * 64 + fkb;
      boff[ks][nf] = row * 128 + (cl ^ ((row & 7) << 4));
    }
  }

  f32x4 acc[4][4] = {};

#define DO_MFMA16(af, bv)                                                      \
  __builtin_amdgcn_s_setprio(1);                                               \
  _Pragma("unroll") for (int i_ = 0; i_ < 4; i_++)                             \
  _Pragma("unroll") for (int nf_ = 0; nf_ < 4; nf_++)                          \
      acc[i_][nf_] = __builtin_amdgcn_mfma_f32_16x16x32_bf16(                  \
          af[i_], bv[nf_], acc[i_][nf_], 0, 0, 0);                             \
  __builtin_amdgcn_s_setprio(0);

  // prologue: stage tiles 0 and 1; wait tile 0 only (counted vmcnt: 8 out -> 4)
  STAGE4(0, 0);
  STAGE4(1, 1);
  asm volatile("s_waitcnt vmcnt(4)" ::: "memory");
  __builtin_amdgcn_s_barrier();

  for (int t = 0; t < NT; ++t) {
    const int cur = t & 1;
    const char* asb = (const char*)&As[cur][0];
    const char* bsb = (const char*)&Bs[cur][0];
    bf16x8 a0[4], b0[4], a1[4], b1[4];

#pragma unroll
    for (int nf = 0; nf < 4; nf++) b0[nf] = *(const bf16x8*)(bsb + boff[0][nf]);
#pragma unroll
    for (int i = 0; i < 4; i++) a0[i] = *(const bf16x8*)(asb + aoff[0][i]);
    DO_MFMA16(a0, b0);
#pragma unroll
    for (int nf = 0; nf < 4; nf++) b1[nf] = *(const bf16x8*)(bsb + boff[1][nf]);
#pragma unroll
    for (int i = 0; i < 4; i++) a1[i] = *(const bf16x8*)(asb + aoff[1][i]);
    __builtin_amdgcn_sched_barrier(0);
    asm volatile("s_waitcnt lgkmcnt(0)" ::: "memory");
    __builtin_amdgcn_s_barrier();          // all waves done reading buf[cur]
    if (t + 2 < NT) STAGE4(cur, t + 2);
    __builtin_amdgcn_sched_barrier(0);
    DO_MFMA16(a1, b1);
    if (t + 2 < NT) {
      asm volatile("s_waitcnt vmcnt(4)" ::: "memory");   // tile t+1 landed
      __builtin_amdgcn_s_barrier();
    } else if (t + 1 < NT) {
      asm volatile("s_waitcnt vmcnt(0)" ::: "memory");   // last tile landed
      __builtin_amdgcn_s_barrier();
    }
    __builtin_amdgcn_sched_barrier(0);
  }

  // ---- epilogue ----
  if (PHASE == 1) {
#pragma unroll
    for (int mf = 0; mf < 4; mf++) {
      int rbase = mt * 256 + wr * 64 + mf * 16 + ((lane >> 4) << 2);
#pragma unroll
      for (int p = 0; p < 2; p++) {
        int hcol = (n0 >> 1) + wc * 32 + p * 16 + fr;
#pragma unroll
        for (int j = 0; j < 4; j++) {
          int r = rbase + j;
          if (r < cnt) {
            float g = acc[mf][2 * p][j];
            float v = acc[mf][2 * p + 1][j];
            float s = g / (1.f + __expf(-g));
            hb[(size_t)(seg + r) * H_DIM + hcol] = (bf16_t)(s * v);
          }
        }
      }
    }
  } else {
    bf16_t* pout = partial + (size_t)khalf * HALFP;
#pragma unroll
    for (int mf = 0; mf < 4; mf++) {
      int rbase = mt * 256 + wr * 64 + mf * 16 + ((lane >> 4) << 2);
#pragma unroll
      for (int j = 0; j < 4; j++) {
        int r = rbase + j;
        if (r < cnt) {
          bf16_t* op = pout + (size_t)(seg + r) * D_EMB + n0 + wc * 64 + fr;
#pragma unroll
          for (int nf = 0; nf < 4; nf++) op[nf * 16] = (bf16_t)acc[mf][nf][j];
        }
      }
    }
  }
#undef STAGE4
#undef DO_MFMA16
}

// ---- combine: out[tok] = p0*(pa0+pa1) + p1*(pb0+pb1) (bf16 split-K partials) ----
__global__ __launch_bounds__(256) void k_combine(const bf16_t* __restrict__ partial,
                                                 const float* __restrict__ tkp,
                                                 const int* __restrict__ tok2pos,
                                                 float* __restrict__ out) {
  int i = blockIdx.x * 256 + threadIdx.x;  // T_TOK*128 threads, 8 elems each
  int tok = i >> 7;
  int c8 = i & 127;
  int p0 = tok2pos[tok * 2], p1 = tok2pos[tok * 2 + 1];
  float w0 = tkp[tok * 2], w1 = tkp[tok * 2 + 1];
  size_t o0 = (size_t)p0 * D_EMB + c8 * 8;
  size_t o1 = (size_t)p1 * D_EMB + c8 * 8;
  bf16x8 a0 = *(const bf16x8*)(partial + o0);
  bf16x8 a1 = *(const bf16x8*)(partial + HALFP + o0);
  bf16x8 b0 = *(const bf16x8*)(partial + o1);
  bf16x8 b1 = *(const bf16x8*)(partial + HALFP + o1);
  float4 r0, r1;
  r0.x = w0 * ((float)a0[0] + (float)a1[0]) + w1 * ((float)b0[0] + (float)b1[0]);
  r0.y = w0 * ((float)a0[1] + (float)a1[1]) + w1 * ((float)b0[1] + (float)b1[1]);
  r0.z = w0 * ((float)a0[2] + (float)a1[2]) + w1 * ((float)b0[2] + (float)b1[2]);
  r0.w = w0 * ((float)a0[3] + (float)a1[3]) + w1 * ((float)b0[3] + (float)b1[3]);
  r1.x = w0 * ((float)a0[4] + (float)a1[4]) + w1 * ((float)b0[4] + (float)b1[4]);
  r1.y = w0 * ((float)a0[5] + (float)a1[5]) + w1 * ((float)b0[5] + (float)b1[5]);
  r1.z = w0 * ((float)a0[6] + (float)a1[6]) + w1 * ((float)b0[6] + (float)b1[6]);
  r1.w = w0 * ((float)a0[7] + (float)a1[7]) + w1 * ((float)b0[7] + (float)b1[7]);
  float4* op = (float4*)(out + (size_t)tok * D_EMB + c8 * 8);
  op[0] = r0;
  op[1] = r1;
}

extern "C" void kernel_launch(void* const* d_in, const int* in_sizes, int n_in,
                              void* d_out, int out_size, void* d_ws, size_t ws_size,
                              hipStream_t stream) {
  (void)in_sizes; (void)n_in; (void)ws_size; (void)out_size;
  const float* x   = (const float*)d_in[0];
  const float* w12 = (const float*)d_in[1];
  const float* w3  = (const float*)d_in[2];
  const float* wg  = (const float*)d_in[3];
  float* out = (float*)d_out;
  char* ws = (char*)d_ws;

  const size_t OFF_XB   = 0;                       // xb: 16 MiB
  const size_t OFF_W12B = 16777216;                // w12b: 64 MiB
  const size_t OFF_W3B  = OFF_W12B + 67108864;     // w3b: 32 MiB
  const size_t OFF_HB   = OFF_W3B + 33554432;      // hb: 64 MiB
  const size_t OFF_META = OFF_HB + 67108864;
  // partial (bf16 2 x 16384x1024 = 64 MiB) overlaps [xb|w12b] — dead by gemm2 time.
  const size_t OFF_PART = 0;

  bf16_t* xb   = (bf16_t*)(ws + OFF_XB);
  bf16_t* w12b = (bf16_t*)(ws + OFF_W12B);
  bf16_t* w3b  = (bf16_t*)(ws + OFF_W3B);
  bf16_t* hb   = (bf16_t*)(ws + OFF_HB);
  bf16_t* partial = (bf16_t*)(ws + OFF_PART);
  int*   offsets   = (int*)(ws + OFF_META);                 // 64 B
  int*   blockhist = (int*)(ws + OFF_META + 64);            // 8 KiB
  int*   tilestart = (int*)(ws + OFF_META + 16448);         // 64 B
  int*   tki       = (int*)(ws + OFF_META + 32768);
  float* tkp       = (float*)(ws + OFF_META + 32768 + 65536);
  int*   tlist     = (int*)(ws + OFF_META + 32768 + 2 * 65536);
  int*   tok2pos   = (int*)(ws + OFF_META + 32768 + 3 * 65536);

  k_pre<<<RBLK + 8192 + 4096, 256, 0, stream>>>(x, wg, w12, w3, xb, w12b, w3b,
                                                tki, tkp, blockhist);
  k_scatter<<<RBLK, 64, 0, stream>>>(blockhist, tki, tlist, tok2pos, offsets, tilestart);
  k_gemm8<1><<<MAXTILES * 16, 1024, 0, stream>>>(xb, w12b, offsets, tilestart, tlist, hb, nullptr);
  k_gemm8<2><<<MAXTILES * 4 * 2, 1024, 0, stream>>>(hb, w3b, offsets, tilestart, tlist, nullptr, partial);
  k_combine<<<T_TOK / 2, 256, 0, stream>>>(partial, tkp, tok2pos, out);
}